// Round 3
// baseline (848.120 us; speedup 1.0000x reference)
//
#include <hip/hip_runtime.h>
#include <hip/hip_bf16.h>

#define E_TOTAL   1600000
#define NV        50000
#define DE        64
#define DV        64
#define DIN       192
#define DHID      128
#define DOUT      64
#define TILE_M    64
#define XS        200          // xb row stride (ushorts), 400 B: dword-stride 100 ≡ 4 mod 32 -> min-aliasing b128 reads
#define HS        136          // hb row stride (ushorts), 272 B: dword-stride 68 ≡ 4 mod 32 -> min-aliasing b128 reads
#define NTILES    (E_TOTAL / TILE_M)   // 25000 exact

typedef __bf16 bf16x8  __attribute__((ext_vector_type(8)));
typedef __bf16 bf16x4  __attribute__((ext_vector_type(4)));
typedef float  floatx4 __attribute__((ext_vector_type(4)));
typedef float  fx4     __attribute__((ext_vector_type(4)));

static __device__ __forceinline__ unsigned short f2bf(float f) {
    unsigned int u = __float_as_uint(f);
    u += 0x7fffu + ((u >> 16) & 1u);   // round-to-nearest-even
    return (unsigned short)(u >> 16);
}

// ---- prep: W1 [192][128] -> w1t bf16 [128][192]; W2 [128][64] -> w2t bf16 [64][128];
//      vfeat fp32 [NV][64] -> vfb bf16 (same layout)
__global__ void prep_kernel(const float* __restrict__ W1, const float* __restrict__ W2,
                            const float* __restrict__ vfeat,
                            unsigned short* __restrict__ w1t,
                            unsigned short* __restrict__ w2t,
                            unsigned short* __restrict__ vfb, int do_vfb) {
    int tid = blockIdx.x * blockDim.x + threadIdx.x;
    int stride = gridDim.x * blockDim.x;
    for (int i = tid; i < DIN * DHID; i += stride) {
        int n = i / DIN, k = i % DIN;
        w1t[i] = f2bf(W1[k * DHID + n]);
    }
    for (int i = tid; i < DHID * DOUT; i += stride) {
        int n = i / DHID, k = i % DHID;
        w2t[i] = f2bf(W2[k * DOUT + n]);
    }
    if (do_vfb) {
        const fx4* src = (const fx4*)vfeat;
        ushort4* dst = (ushort4*)vfb;
        int n4 = NV * DV / 4;
        for (int i = tid; i < n4; i += stride) {
            fx4 v = src[i];
            ushort4 o;
            o.x = f2bf(v[0]); o.y = f2bf(v[1]); o.z = f2bf(v[2]); o.w = f2bf(v[3]);
            dst[i] = o;
        }
    }
}

// Round-3: r0's serial 3-barrier schedule + nt stores (measured fastest; regular
// stores cost +101us via L2 eviction of the 6.4MB vfb table -> gathers fall to L3).
// Single change: L2 output mapping wave->16 FULL ROWS (was wave->16-col slice).
// Each 256-B out row is now written entirely by ONE wave in 4 back-to-back fx4
// nt stores -> nt lines are fully dirty when evicted -> kills the 1.69x write
// amplification measured in r1 (128-B lines previously split across 2 waves).
// Each wave holds all of W2^T in regs (w2f[4][4], 64 VGPR); hb reads drop 16->4.
// L1 runs in two mb-halves to cap live VGPRs (~160 <= 170 for 3 waves/SIMD).
template <bool USE_VFB>
__global__ __launch_bounds__(256, 3) void edge_mlp(
    const float* __restrict__ edata,
    const float* __restrict__ vfeat,
    const float* __restrict__ b1,
    const float* __restrict__ b2,
    const int* __restrict__ senders,
    const int* __restrict__ receivers,
    const unsigned short* __restrict__ w1t,
    const unsigned short* __restrict__ w2t,
    const unsigned short* __restrict__ vfb,
    float* __restrict__ out) {
    __shared__ unsigned short xb[TILE_M * XS];   // 25600 B
    __shared__ unsigned short hb[TILE_M * HS];   // 17408 B  (43008 B total -> 3 blocks/CU)

    const int tid  = threadIdx.x;
    const int lane = tid & 63;
    const int wave = tid >> 6;
    const int l15  = lane & 15;
    const int quad = lane >> 4;

    // ---- weight fragments (MFMA A-operand layout: lane&15 = row n, k = quad*8+j)
    bf16x8 w1f[6][2];   // W1^T rows n = wave*32 + nb*16 + l15           (48 VGPR)
    bf16x8 w2f[4][4];   // [nbk][ks]: W2^T rows n = nbk*16 + l15, ALL n  (64 VGPR)
    {
#pragma unroll
        for (int nb = 0; nb < 2; ++nb) {
            const unsigned short* p = w1t + (wave * 32 + nb * 16 + l15) * DIN + quad * 8;
#pragma unroll
            for (int ks = 0; ks < 6; ++ks)
                w1f[ks][nb] = *(const bf16x8*)(p + ks * 32);
        }
#pragma unroll
        for (int nbk = 0; nbk < 4; ++nbk) {
            const unsigned short* p2 = w2t + (nbk * 16 + l15) * DHID + quad * 8;
#pragma unroll
            for (int ks = 0; ks < 4; ++ks)
                w2f[nbk][ks] = *(const bf16x8*)(p2 + ks * 32);
        }
    }
    // Swapped-operand C layout: D row (= quad*4+r) indexes the n dimension.
    fx4 b1v[2], b2v[4];
#pragma unroll
    for (int nb = 0; nb < 2; ++nb)
        b1v[nb] = *(const fx4*)(b1 + wave * 32 + nb * 16 + quad * 4);
#pragma unroll
    for (int nbk = 0; nbk < 4; ++nbk)
        b2v[nbk] = *(const fx4*)(b2 + nbk * 16 + quad * 4);

    for (int t = blockIdx.x; t < NTILES; t += gridDim.x) {
        const long e0 = (long)t * TILE_M;

        // ---- stage x tile: [64 edges][192 bf16] = edata | vfeat[recv] | vfeat[send]
        {
#pragma unroll
            for (int it = 0; it < 4; ++it) {
                int idx = it * 256 + tid;
                int e = idx >> 4;
                int c = idx & 15;
                fx4 v = __builtin_nontemporal_load((const fx4*)(edata + (e0 + e) * DE + c * 4));
                bf16x4 o;
                o[0] = (__bf16)v[0]; o[1] = (__bf16)v[1];
                o[2] = (__bf16)v[2]; o[3] = (__bf16)v[3];
                *(bf16x4*)(xb + e * XS + c * 4) = o;
            }
            if constexpr (USE_VFB) {
#pragma unroll
                for (int it = 0; it < 4; ++it) {
                    int idx = it * 256 + tid;
                    int e = idx >> 4;
                    int g = (idx >> 3) & 1;
                    int c = idx & 7;
                    int row = g ? senders[e0 + e] : receivers[e0 + e];
                    uint4 v = *(const uint4*)(vfb + row * DV + c * 8);
                    *(uint4*)(xb + e * XS + DE + g * DV + c * 8) = v;
                }
            } else {
#pragma unroll
                for (int it = 0; it < 8; ++it) {
                    int idx = it * 256 + tid;
                    int e = idx >> 5;
                    int g = (idx >> 4) & 1;
                    int c = idx & 15;
                    int row = g ? senders[e0 + e] : receivers[e0 + e];
                    fx4 v = *(const fx4*)(vfeat + (long)row * DV + c * 4);
                    bf16x4 o;
                    o[0] = (__bf16)v[0]; o[1] = (__bf16)v[1];
                    o[2] = (__bf16)v[2]; o[3] = (__bf16)v[3];
                    *(bf16x4*)(xb + e * XS + DE + g * DV + c * 4) = o;
                }
            }
        }
        __syncthreads();

        // ---- layer 1 (two mb-halves to cap live VGPRs):
        // C = mfma(W1^T-frag, x-frag) -> lane holds h[e=l15][n = quad*4+r],
        // relu+pack -> one 8-B LDS write per fragment into hb[e][hidden]
#pragma unroll
        for (int half = 0; half < 2; ++half) {
            floatx4 acc[2][2];
#pragma unroll
            for (int m = 0; m < 2; ++m)
#pragma unroll
                for (int nb = 0; nb < 2; ++nb)
                    acc[m][nb] = (floatx4){b1v[nb][0], b1v[nb][1], b1v[nb][2], b1v[nb][3]};
#pragma unroll
            for (int ks = 0; ks < 6; ++ks) {
                bf16x8 a[2];
#pragma unroll
                for (int m = 0; m < 2; ++m)
                    a[m] = *(const bf16x8*)(xb + ((half * 2 + m) * 16 + l15) * XS + ks * 32 + quad * 8);
#pragma unroll
                for (int m = 0; m < 2; ++m)
#pragma unroll
                    for (int nb = 0; nb < 2; ++nb)
                        acc[m][nb] = __builtin_amdgcn_mfma_f32_16x16x32_bf16(
                            w1f[ks][nb], a[m], acc[m][nb], 0, 0, 0);
            }
#pragma unroll
            for (int m = 0; m < 2; ++m)
#pragma unroll
                for (int nb = 0; nb < 2; ++nb) {
                    bf16x4 o;
#pragma unroll
                    for (int r = 0; r < 4; ++r) {
                        float v = acc[m][nb][r];
                        o[r] = (__bf16)(v > 0.f ? v : 0.f);
                    }
                    *(bf16x4*)(hb + ((half * 2 + m) * 16 + l15) * HS
                               + wave * 32 + nb * 16 + quad * 4) = o;
                }
        }
        __syncthreads();   // hb ready; all xb(t) reads done

        // ---- layer 2: wave owns rows e = wave*16 + l15, ALL 64 output cols.
        // C = mfma(W2^T-frag, h-frag); ONE hb read per ks feeds 4 MFMAs.
        floatx4 acc2[4];
#pragma unroll
        for (int nbk = 0; nbk < 4; ++nbk)
            acc2[nbk] = (floatx4){b2v[nbk][0], b2v[nbk][1], b2v[nbk][2], b2v[nbk][3]};
#pragma unroll
        for (int ks = 0; ks < 4; ++ks) {
            bf16x8 a2 = *(const bf16x8*)(hb + (wave * 16 + l15) * HS + ks * 32 + quad * 8);
#pragma unroll
            for (int nbk = 0; nbk < 4; ++nbk)
                acc2[nbk] = __builtin_amdgcn_mfma_f32_16x16x32_bf16(
                    w2f[nbk][ks], a2, acc2[nbk], 0, 0, 0);
        }

        // lane holds out[e = wave*16+l15][nbk*16 + quad*4 .. +3]; the wave's 4
        // back-to-back nt stores cover each of its 16 rows' full 256 B ->
        // both 128-B lines fully dirty inside the write-combine window.
#pragma unroll
        for (int nbk = 0; nbk < 4; ++nbk)
            __builtin_nontemporal_store(acc2[nbk],
                (fx4*)(out + (e0 + wave * 16 + l15) * DOUT + nbk * 16 + quad * 4));

        __syncthreads();   // r0's 3rd barrier: keep — r0 measured fastest with it
    }
}

extern "C" void kernel_launch(void* const* d_in, const int* in_sizes, int n_in,
                              void* d_out, int out_size, void* d_ws, size_t ws_size,
                              hipStream_t stream) {
    const float* edata     = (const float*)d_in[0];
    const float* vfeat     = (const float*)d_in[1];
    const float* W1        = (const float*)d_in[2];
    const float* b1        = (const float*)d_in[3];
    const float* W2        = (const float*)d_in[4];
    const float* b2        = (const float*)d_in[5];
    const int*   senders   = (const int*)d_in[6];
    const int*   receivers = (const int*)d_in[7];
    float* out = (float*)d_out;

    unsigned short* w1t = (unsigned short*)d_ws;
    unsigned short* w2t = w1t + DIN * DHID;
    unsigned short* vfb = w2t + DHID * DOUT;
    const size_t need_vfb = (size_t)(DIN * DHID + DHID * DOUT + NV * DV) * sizeof(unsigned short);
    const bool use_vfb = ws_size >= need_vfb;

    prep_kernel<<<512, 256, 0, stream>>>(W1, W2, vfeat, w1t, w2t, vfb, use_vfb ? 1 : 0);
    if (use_vfb)
        edge_mlp<true><<<1536, 256, 0, stream>>>(edata, vfeat, b1, b2, senders, receivers,
                                                 w1t, w2t, vfb, out);
    else
        edge_mlp<false><<<1536, 256, 0, stream>>>(edata, vfeat, b1, b2, senders, receivers,
                                                  w1t, w2t, vfb, out);
}